// Round 2
// 390.165 us; speedup vs baseline: 1.2071x; 1.2071x over previous
//
#include <hip/hip_runtime.h>
#include <math.h>

namespace {
constexpr int N_TOK  = 8192;
constexpr int GROUPS = 4;
constexpr int D      = 128;
} // namespace

typedef short v8s __attribute__((ext_vector_type(8)));
typedef float v4f __attribute__((ext_vector_type(4)));

__device__ __forceinline__ short f2bf(float f) {
    union { float f; unsigned u; } x; x.f = f;
    unsigned r = x.u + 0x7FFFu + ((x.u >> 16) & 1u);
    return (short)(r >> 16);
}

// ---------------------------------------------------------------------------
// Build M^T [128 cols][1024 k] bf16 in workspace.  (unchanged — ~5 us)
// ---------------------------------------------------------------------------
__global__ __launch_bounds__(256)
void build_MT(const float* __restrict__ widx,  // [32][16][16]
              const float* __restrict__ wn,    // [64][960]
              short* __restrict__ MT)          // [128][1024]
{
    const int idx = blockIdx.x * 256 + threadIdx.x;   // 131072 total
    const int col = idx >> 10;
    const int kk  = idx & 1023;
    const int g   = kk >> 7;
    const int dp  = kk & 127;
    const int part = dp >> 6;
    const int dpp  = dp & 63;
    const int B    = (dpp & 1) * 16 + (dpp >> 2);
    const int c    = g + 8 * ((dpp >> 1) & 1);

    float val;
    if (col < 64) {
        val = (col == part * 32 + B) ? widx[B * 256 + c * 16] : 0.f;
    } else {
        const int d2 = col - 64;
        const float* wrow = wn + d2 * 960 + part * 480 + B * 15;
        const float* wi   = widx + B * 256 + c * 16;
        float s = 0.f;
#pragma unroll
        for (int o = 1; o < 16; ++o) s += wi[o] * wrow[o - 1];
        val = s;
    }
    MT[idx] = f2bf(val);
}

// ---------------------------------------------------------------------------
// Main GEMM: Out[40960][128] = A[40960][1024] x M[1024][128]
// Column-half split: blockIdx bit0 selects rope cols (0..63, A from q/k) or
// nope cols (64..127, A from q_orig/k_orig). Each A element is read by
// exactly ONE block either way -> 2x waves (20/CU) at identical HBM traffic.
// Per wave: 16 rows x 64 cols; per ks-iter: 2 float4 A-loads (32 B/lane),
// 4 B-frag loads (L1/L2-resident MT), 4 MFMA. unroll 4 -> ~8 A-loads in
// flight per wave for latency hiding.
// ---------------------------------------------------------------------------
__global__ __launch_bounds__(256, 4)
void gemm_kernel(const float* __restrict__ q,       // [N,32,128]
                 const float* __restrict__ k,       // [N,8,128]
                 const float* __restrict__ q_orig,  // [N,32,128]
                 const float* __restrict__ k_orig,  // [N,8,128]
                 const short* __restrict__ MT,      // [128][1024] bf16
                 float* __restrict__ out_iq,        // [N,4,128]
                 float* __restrict__ out_ik)        // [N,128]
{
    const int lane = threadIdx.x & 63;
    const int wave = threadIdx.x >> 6;
    const int m    = lane & 15;
    const int quad = lane >> 4;
    const int half = blockIdx.x & 1;                   // 0 = rope, 1 = nope
    const int base_row = (blockIdx.x >> 1) * 64 + wave * 16;

    // per-lane A row
    const int row = base_row + m;
    const int n   = row / 5;
    const int jj  = row - n * 5;
    const bool isq = (jj < 4);
    const float* ap;
    if (half == 0) ap = isq ? (q      + n * 4096 + jj * 128) : (k      + n * 1024);
    else           ap = isq ? (q_orig + n * 4096 + jj * 128) : (k_orig + n * 1024);

    const short* bbase = MT + (half * 64 + m) * 1024;

    v4f acc[4];
#pragma unroll
    for (int t = 0; t < 4; ++t) acc[t] = (v4f){0.f, 0.f, 0.f, 0.f};

#pragma unroll 4
    for (int ks = 0; ks < 32; ++ks) {
        const int kk   = ks * 32 + quad * 8;
        const int offA = isq ? ((kk >> 7) * 512 + (kk & 127)) : kk;
        const float4 r0 = *(const float4*)(ap + offA);
        const float4 r1 = *(const float4*)(ap + offA + 4);
        v8s a;
        a[0] = f2bf(r0.x); a[1] = f2bf(r0.y); a[2] = f2bf(r0.z); a[3] = f2bf(r0.w);
        a[4] = f2bf(r1.x); a[5] = f2bf(r1.y); a[6] = f2bf(r1.z); a[7] = f2bf(r1.w);

        const short* bp = bbase + kk;
#pragma unroll
        for (int t = 0; t < 4; ++t) {
            const v8s b = *(const v8s*)(bp + t * 16384);  // t*16 cols * 1024
            acc[t] = __builtin_amdgcn_mfma_f32_16x16x32_bf16(a, b, acc[t], 0, 0, 0);
        }
    }

    // C/D layout: col = lane&15, row_in_tile = quad*4 + reg
#pragma unroll
    for (int t = 0; t < 4; ++t) {
        const int col = half * 64 + t * 16 + m;
#pragma unroll
        for (int i = 0; i < 4; ++i) {
            const int r2  = base_row + quad * 4 + i;
            const int n2  = r2 / 5;
            const int jj2 = r2 - n2 * 5;
            float* dst = (jj2 < 4) ? (out_iq + n2 * 512 + jj2 * 128)
                                   : (out_ik + n2 * 128);
            dst[col] = acc[t][i];
        }
    }
}

// ---------------------------------------------------------------------------
// Weights: w[n,h,rr] = sum_d v[n,h>>2,d] * vt[h,d,rr];
// weights[n,j] = ||{w[n,g*4+j,rr] : g,rr}||_2.
// 512 threads = 16 tokens x 32 h. vt (64 KB) staged in LDS once per block,
// XOR-swizzled (float4 index ^ (h&7)) so the 4 distinct h-addresses per
// wave land in distinct banks. All loads are float4; per thread:
// 32 global float4 (v row) + 128 LDS b128 — no scalar global loads.
// ---------------------------------------------------------------------------
__global__ __launch_bounds__(512)
void weights_kernel(const float* __restrict__ v,    // [N,8,128]
                    const float* __restrict__ vt,   // [32,128,4]
                    float* __restrict__ out_w)      // [N,4]
{
    __shared__ float4 s_vt[4096];                    // 64 KB, reused for reduce
    const int tid = threadIdx.x;

    const float4* vt4 = (const float4*)vt;
#pragma unroll
    for (int i0 = 0; i0 < 8; ++i0) {
        const int i   = i0 * 512 + tid;
        const int hh  = i >> 7;
        const int low = i & 127;
        s_vt[(i & ~127) | (low ^ (hh & 7))] = vt4[i];
    }
    __syncthreads();

    const int tok_l = tid & 15;        // 0..15
    const int h     = tid >> 4;        // 0..31  (wave w -> h in {4w..4w+3})
    const int g     = h >> 2;
    const int sw    = h & 7;
    const int token = blockIdx.x * 16 + tok_l;

    const float4* vrow = (const float4*)(v + token * 1024 + g * 128);
    const float4* wrow = s_vt + h * 128;

    float ax = 0.f, ay = 0.f, az = 0.f, aw = 0.f;
#pragma unroll 8
    for (int d4 = 0; d4 < 32; ++d4) {
        const float4 vv = vrow[d4];
        {
            const float4 w0 = wrow[(d4 * 4 + 0) ^ sw];
            ax += vv.x * w0.x; ay += vv.x * w0.y; az += vv.x * w0.z; aw += vv.x * w0.w;
        }
        {
            const float4 w1 = wrow[(d4 * 4 + 1) ^ sw];
            ax += vv.y * w1.x; ay += vv.y * w1.y; az += vv.y * w1.z; aw += vv.y * w1.w;
        }
        {
            const float4 w2 = wrow[(d4 * 4 + 2) ^ sw];
            ax += vv.z * w2.x; ay += vv.z * w2.y; az += vv.z * w2.z; aw += vv.z * w2.w;
        }
        {
            const float4 w3 = wrow[(d4 * 4 + 3) ^ sw];
            ax += vv.w * w3.x; ay += vv.w * w3.y; az += vv.w * w3.z; aw += vv.w * w3.w;
        }
    }
    const float s = ax * ax + ay * ay + az * az + aw * aw;

    __syncthreads();                    // all s_vt reads done
    float* s_red = (float*)s_vt;
    s_red[tok_l * 32 + h] = s;          // layout [tok][h = g*4+j]
    __syncthreads();
    if (tid < 64) {
        const int tok = tid & 15;
        const int j   = tid >> 4;       // 0..3
        const float* p = s_red + tok * 32 + j;
        float t = 0.f;
#pragma unroll
        for (int g2 = 0; g2 < 8; ++g2) t += p[g2 * 4];
        out_w[(blockIdx.x * 16 + tok) * 4 + j] = sqrtf(t);
    }
}

extern "C" void kernel_launch(void* const* d_in, const int* in_sizes, int n_in,
                              void* d_out, int out_size, void* d_ws, size_t ws_size,
                              hipStream_t stream) {
    const float* q      = (const float*)d_in[0];
    const float* k      = (const float*)d_in[1];
    const float* v      = (const float*)d_in[2];
    const float* q_orig = (const float*)d_in[3];
    const float* k_orig = (const float*)d_in[4];
    const float* widx   = (const float*)d_in[5];
    const float* wn     = (const float*)d_in[6];
    const float* vt     = (const float*)d_in[7];

    float* out_iq = (float*)d_out;
    float* out_ik = out_iq + (size_t)N_TOK * GROUPS * D;  // +4,194,304
    float* out_w  = out_ik + (size_t)N_TOK * D;           // +1,048,576

    short* MT = (short*)d_ws;  // 128*1024 bf16 = 256 KB

    hipLaunchKernelGGL(build_MT, dim3(512), dim3(256), 0, stream, widx, wn, MT);
    hipLaunchKernelGGL(gemm_kernel, dim3(1280), dim3(256), 0, stream,
                       q, k, q_orig, k_orig, MT, out_iq, out_ik);
    hipLaunchKernelGGL(weights_kernel, dim3(512), dim3(512), 0, stream,
                       v, vt, out_w);
}